// Round 4
// baseline (732.992 us; speedup 1.0000x reference)
//
#include <hip/hip_runtime.h>
#include <cstdint>
#include <cstddef>

#define DDIM 4096          // hidden dim
#define D4   1024          // float4 per token row
#define NE   16            // experts
#define KC4  128           // K-chunk in float4 (512 floats)
#define NCHUNK 8           // DDIM/512
#define SCHUNK 256         // scatter chunk (tokens)

// async 16B global->LDS (lane's data lands at ldsbase + lane*16)
__device__ __forceinline__ void load_lds16(const void* g, void* l) {
    __builtin_amdgcn_global_load_lds(
        (const __attribute__((address_space(1))) unsigned int*)g,
        (__attribute__((address_space(3))) unsigned int*)l, 16, 0, 0);
}

__device__ __forceinline__ float dot4(float4 a, float4 w) {
    return a.x * w.x + a.y * w.y + a.z * w.z + a.w * w.w;
}

// ---------------------------------------------------------------------------
// Pass A: logits + top-2 softmax renorm + dispatch + packed pair byte +
// per-256-token-chunk expert histogram (global atomics).
// Block = 4 waves = 32 tokens. W staged chunk-wise (32 KB) into LDS via
// global_load_lds. Wave layout: tg = lane>>4 (4 groups x 2 tokens),
// kl = lane&15 (K-slice). acc = 2 tokens x 16 experts = 32 VGPRs.
// ---------------------------------------------------------------------------
__global__ __launch_bounds__(256, 4) void router_pass_a(
    const float* __restrict__ x, const float* __restrict__ W,
    const float* __restrict__ b, float* __restrict__ out,
    unsigned char* __restrict__ packed, int* __restrict__ gcounts, int T)
{
    __shared__ float4 shW4[NE * KC4];   // 32 KB: [e][128 float4]

    const int tid  = (int)threadIdx.x;
    const int lane = tid & 63;
    const int wid  = tid >> 6;                    // wave in block
    const int tg   = lane >> 4;                   // token-pair group
    const int kl   = lane & 15;                   // K-lane
    const int tok0 = ((int)blockIdx.x * 4 + wid) * 8 + tg * 2;

    const float4* __restrict__ x4 = (const float4*)x;
    const float4* __restrict__ W4 = (const float4*)W;
    const float4* xr0 = x4 + (size_t)tok0 * D4;   // token tok0
    const float4* xr1 = xr0 + D4;                 // token tok0+1

    float acc0[NE], acc1[NE];
#pragma unroll
    for (int e = 0; e < NE; ++e) { acc0[e] = 0.f; acc1[e] = 0.f; }

    for (int kc = 0; kc < NCHUNK; ++kc) {
        if (kc) __syncthreads();   // prior chunk fully consumed before overwrite
        // stage 32 KB W chunk: 32 wave-issues, 8 per wave, 1 KB each
#pragma unroll
        for (int j = 0; j < 8; ++j) {
            const int slot = wid * 8 + j;          // 0..31
            const int e = slot >> 1, half = slot & 1;
            const float4* g = W4 + (size_t)e * D4 + kc * KC4 + half * 64 + lane;
            load_lds16((const void*)g, (void*)(shW4 + slot * 64));
        }
        __syncthreads();           // drains vmcnt -> staging visible

        const int base = kc * KC4;
#pragma unroll 4
        for (int i = 0; i < 8; ++i) {
            const int f = base + kl + (i << 4);
            float4 a0 = xr0[f];
            float4 a1 = xr1[f];
            const float4* wrow = shW4 + kl + (i << 4);
#pragma unroll
            for (int e = 0; e < NE; ++e) {
                float4 w = wrow[e * KC4];
                acc0[e] += dot4(a0, w);
                acc1[e] += dot4(a1, w);
            }
        }
    }

    // split-exchange within each 16-lane group: acc0[0]/acc1[0] end up holding
    // the full sum for expert e == kl.
#pragma unroll
    for (int m = 8; m >= 1; m >>= 1) {
        const bool hi = (kl & m) != 0;
#pragma unroll
        for (int i = 0; i < m; ++i) {
            float s0 = hi ? acc0[i] : acc0[i + m];
            float k0 = hi ? acc0[i + m] : acc0[i];
            acc0[i] = k0 + __shfl_xor(s0, m, 64);
            float s1 = hi ? acc1[i] : acc1[i + m];
            float k1 = hi ? acc1[i + m] : acc1[i];
            acc1[i] = k1 + __shfl_xor(s1, m, 64);
        }
    }

    const float logit0 = acc0[0] + b[kl];
    const float logit1 = acc1[0] + b[kl];
    out[(size_t)tok0 * NE + kl]       = logit0;
    out[(size_t)(tok0 + 1) * NE + kl] = logit1;

    // top-2 merge over the 16-lane group (lower index wins ties), both tokens
    float m1a = logit0; int i1a = kl; float m2a = -__builtin_inff(); int i2a = NE;
    float m1b = logit1; int i1b = kl; float m2b = -__builtin_inff(); int i2b = NE;
#pragma unroll
    for (int m = 1; m <= 8; m <<= 1) {
        {
            float om1 = __shfl_xor(m1a, m, 64); int oi1 = __shfl_xor(i1a, m, 64);
            float om2 = __shfl_xor(m2a, m, 64); int oi2 = __shfl_xor(i2a, m, 64);
            bool aF = (m1a > om1) || (m1a == om1 && i1a < oi1);
            float n1v = aF ? m1a : om1; int n1i = aF ? i1a : oi1;
            float l1v = aF ? om1 : m1a; int l1i = aF ? oi1 : i1a;
            float c2v = aF ? m2a : om2; int c2i = aF ? i2a : oi2;
            bool s = (l1v > c2v) || (l1v == c2v && l1i < c2i);
            m1a = n1v; i1a = n1i; m2a = s ? l1v : c2v; i2a = s ? l1i : c2i;
        }
        {
            float om1 = __shfl_xor(m1b, m, 64); int oi1 = __shfl_xor(i1b, m, 64);
            float om2 = __shfl_xor(m2b, m, 64); int oi2 = __shfl_xor(i2b, m, 64);
            bool aF = (m1b > om1) || (m1b == om1 && i1b < oi1);
            float n1v = aF ? m1b : om1; int n1i = aF ? i1b : oi1;
            float l1v = aF ? om1 : m1b; int l1i = aF ? oi1 : i1b;
            float c2v = aF ? m2b : om2; int c2i = aF ? i2b : oi2;
            bool s = (l1v > c2v) || (l1v == c2v && l1i < c2i);
            m1b = n1v; i1b = n1i; m2b = s ? l1v : c2v; i2b = s ? l1i : c2i;
        }
    }

    float* __restrict__ disp = out + (size_t)T * NE;
    {
        const float q = expf(m2a - m1a);
        const float r1 = 1.f / (1.f + q), r2 = q / (1.f + q);
        disp[(size_t)tok0 * NE + kl] = (kl == i1a) ? r1 : ((kl == i2a) ? r2 : 0.f);
    }
    {
        const float q = expf(m2b - m1b);
        const float r1 = 1.f / (1.f + q), r2 = q / (1.f + q);
        disp[(size_t)(tok0 + 1) * NE + kl] = (kl == i1b) ? r1 : ((kl == i2b) ? r2 : 0.f);
    }

    if (kl == 0) {
        packed[tok0]     = (unsigned char)(i1a | (i2a << 4));
        packed[tok0 + 1] = (unsigned char)(i1b | (i2b << 4));
        int* gc = gcounts + (size_t)(tok0 >> 8) * NE;
        atomicAdd(&gc[i1a], 1);
        atomicAdd(&gc[i2a], 1);
        atomicAdd(&gc[i1b], 1);
        atomicAdd(&gc[i2b], 1);
    }
}

// ---------------------------------------------------------------------------
// Prologue: -1-fill expert_indices, zero the per-chunk histogram.
// Runs before pass_a (no dependency). 256 blocks x 256 threads.
// ---------------------------------------------------------------------------
__global__ __launch_bounds__(256) void router_fill(
    float* __restrict__ idxout, int* __restrict__ gcounts)
{
    const int t = (int)(blockIdx.x * 256 + threadIdx.x);   // 65536 threads
    float4* o4 = (float4*)idxout;                          // 1 MB of -1
    o4[t] = make_float4(-1.f, -1.f, -1.f, -1.f);
    if (t < (16384 / SCHUNK) * NE) gcounts[t] = 0;
}

// ---------------------------------------------------------------------------
// Scatter: stable compaction. 64 blocks x 256 tokens; per-block inline
// exclusive prefix over gcounts, ballot/popcount intra-block ranking.
// ---------------------------------------------------------------------------
__global__ __launch_bounds__(SCHUNK) void router_scatter(
    const unsigned char* __restrict__ packed, const int* __restrict__ gcounts,
    float* __restrict__ idxout, int T)
{
    const int c    = (int)blockIdx.x;
    const int tid  = (int)threadIdx.x;
    const int lane = tid & 63;
    const int wid  = tid >> 6;              // 0..3
    __shared__ int offs[NE];
    __shared__ int wtot[SCHUNK / 64][NE];

    if (tid < NE) {
        int o = 0;
        for (int cc = 0; cc < c; ++cc) o += gcounts[cc * NE + tid];
        offs[tid] = o;
    }

    const int t = c * SCHUNK + tid;
    const unsigned p = packed[t];
    const int e1 = (int)(p & 15);
    const int e2 = (int)(p >> 4);

    unsigned long long bal[NE];
#pragma unroll
    for (int ee = 0; ee < NE; ++ee)
        bal[ee] = __ballot((e1 == ee) || (e2 == ee));

    if (lane < NE) wtot[wid][lane] = __popcll(bal[lane]);
    __syncthreads();

    const unsigned long long lt = (1ull << lane) - 1ull;
    int r1 = __popcll(bal[e1] & lt);
    int r2 = __popcll(bal[e2] & lt);
    for (int w = 0; w < wid; ++w) { r1 += wtot[w][e1]; r2 += wtot[w][e2]; }

    idxout[(size_t)e1 * T + offs[e1] + r1] = (float)t;
    idxout[(size_t)e2 * T + offs[e2] + r2] = (float)t;
}

extern "C" void kernel_launch(void* const* d_in, const int* in_sizes, int n_in,
                              void* d_out, int out_size, void* d_ws, size_t ws_size,
                              hipStream_t stream)
{
    const float* x = (const float*)d_in[0];
    const float* W = (const float*)d_in[1];
    const float* b = (const float*)d_in[2];
    float* out = (float*)d_out;

    const int T = in_sizes[0] / DDIM;       // 16384 tokens

    unsigned char* packed = (unsigned char*)d_ws;
    int* gcounts = (int*)((char*)d_ws + (((size_t)T + 255) & ~(size_t)255));

    float* idxout = out + (size_t)2 * T * NE;

    // 1) -1 fill + zero histograms (independent of pass_a)
    router_fill<<<(NE * T / 4) / 256, 256, 0, stream>>>(idxout, gcounts);

    // 2) logits/top2/dispatch + histogram: block = 32 tokens
    router_pass_a<<<T / 32, 256, 0, stream>>>(x, W, b, out, packed, gcounts, T);

    // 3) stable scatter of token ids
    router_scatter<<<T / SCHUNK, SCHUNK, 0, stream>>>(packed, gcounts, idxout, T);
}

// Round 5
// 489.170 us; speedup vs baseline: 1.4984x; 1.4984x over previous
//
#include <hip/hip_runtime.h>
#include <cstdint>
#include <cstddef>

#define DDIM 4096          // hidden dim
#define D4   1024          // float4 per token row
#define NE   16            // experts
#define SCHUNK 256         // scatter chunk (tokens)

__device__ __forceinline__ float dot4(float4 a, float4 w) {
    return a.x * w.x + a.y * w.y + a.z * w.z + a.w * w.w;
}

// ---------------------------------------------------------------------------
// Pass A: logits GEMV + bias + top-2 softmax renorm + dispatch tensor +
// packed pair byte + per-256-token-chunk histogram.
// No LDS, no barriers (R1 structure, proven 52-VGPR no-spill).
// Wave = 4 tokens: tg = lane>>4 picks the token, kl = lane&15 is the K-slice
// (float4 idx = kl + 16*i, i in [0,64)). acc[16] = 16 experts for one token.
// Distance-2 register prefetch on x hides HBM latency; W served by L2
// (broadcast across the 4 groups within each wave-load).
// Grid = T/16 blocks of 256 -> 4 blocks/CU, 16 waves/CU.
// ---------------------------------------------------------------------------
__global__ __launch_bounds__(256, 4) void router_pass_a(
    const float* __restrict__ x, const float* __restrict__ W,
    const float* __restrict__ b, float* __restrict__ out,
    unsigned char* __restrict__ packed, int* __restrict__ gcounts, int T)
{
    const int tid  = (int)threadIdx.x;
    const int lane = tid & 63;
    const int tg   = lane >> 4;                   // token within wave
    const int kl   = lane & 15;                   // K-lane
    const int wave = (int)blockIdx.x * 4 + (tid >> 6);
    const int tok  = wave * 4 + tg;

    const float4* __restrict__ x4 = (const float4*)x;
    const float4* __restrict__ W4 = (const float4*)W;
    const float4* xr = x4 + (size_t)tok * D4;

    float acc[NE];
#pragma unroll
    for (int e = 0; e < NE; ++e) acc[e] = 0.f;

    // distance-2 rotating x prefetch (wrap-indexed: always in-bounds, no branch)
    float4 xa = xr[kl];
    float4 xb = xr[kl + 16];
    for (int i = 0; i < 64; ++i) {
        const int nf = ((i + 2) & 63) << 4;
        float4 xn = xr[kl + nf];
        const float4* wp = W4 + kl + (i << 4);
#pragma unroll
        for (int e = 0; e < NE; ++e) {
            float4 w = wp[(size_t)e * D4];
            acc[e] += dot4(xa, w);
        }
        xa = xb; xb = xn;
    }

    // split-exchange within each 16-lane group (xor masks 8,4,2,1 stay in
    // group): acc[0] ends holding the full sum for expert e == kl.
#pragma unroll
    for (int m = 8; m >= 1; m >>= 1) {
        const bool hi = (kl & m) != 0;
#pragma unroll
        for (int j = 0; j < m; ++j) {
            float send = hi ? acc[j] : acc[j + m];
            float keep = hi ? acc[j + m] : acc[j];
            acc[j] = keep + __shfl_xor(send, m, 64);
        }
    }

    const float logit = acc[0] + b[kl];
    out[(size_t)tok * NE + kl] = logit;    // wave writes 64 consecutive floats

    // top-2 (value,index) merge across the 16-lane group; lower index wins ties
    float m1 = logit; int i1 = kl;
    float m2 = -__builtin_inff(); int i2 = NE;
#pragma unroll
    for (int m = 1; m <= 8; m <<= 1) {
        float om1 = __shfl_xor(m1, m, 64); int oi1 = __shfl_xor(i1, m, 64);
        float om2 = __shfl_xor(m2, m, 64); int oi2 = __shfl_xor(i2, m, 64);
        bool aF = (m1 > om1) || (m1 == om1 && i1 < oi1);
        float n1v = aF ? m1 : om1;  int n1i = aF ? i1 : oi1;
        float l1v = aF ? om1 : m1;  int l1i = aF ? oi1 : i1;   // loser of firsts
        float c2v = aF ? m2 : om2;  int c2i = aF ? i2 : oi2;   // winner's 2nd
        bool s = (l1v > c2v) || (l1v == c2v && l1i < c2i);
        m1 = n1v; i1 = n1i;
        m2 = s ? l1v : c2v; i2 = s ? l1i : c2i;
    }

    const float q  = expf(m2 - m1);        // p2/p1
    const float r1 = 1.f / (1.f + q);
    const float r2 = q / (1.f + q);
    float* __restrict__ disp = out + (size_t)T * NE;
    disp[(size_t)tok * NE + kl] = (kl == i1) ? r1 : ((kl == i2) ? r2 : 0.f);

    if (kl == 0) {
        packed[tok] = (unsigned char)(i1 | (i2 << 4));
        int* gc = gcounts + (size_t)(tok >> 8) * NE;
        atomicAdd(&gc[i1], 1);
        atomicAdd(&gc[i2], 1);
    }
}

// ---------------------------------------------------------------------------
// Prologue: -1-fill expert_indices, zero the per-chunk histogram.
// Runs before pass_a (no dependency). 256 blocks x 256 threads.
// ---------------------------------------------------------------------------
__global__ __launch_bounds__(256) void router_fill(
    float* __restrict__ idxout, int* __restrict__ gcounts)
{
    const int t = (int)(blockIdx.x * 256 + threadIdx.x);   // 65536 threads
    float4* o4 = (float4*)idxout;                          // 1 MB of -1
    o4[t] = make_float4(-1.f, -1.f, -1.f, -1.f);
    if (t < (16384 / SCHUNK) * NE) gcounts[t] = 0;
}

// ---------------------------------------------------------------------------
// Scatter: stable compaction. 64 blocks x 256 tokens; per-block inline
// exclusive prefix over gcounts, ballot/popcount intra-block ranking.
// ---------------------------------------------------------------------------
__global__ __launch_bounds__(SCHUNK) void router_scatter(
    const unsigned char* __restrict__ packed, const int* __restrict__ gcounts,
    float* __restrict__ idxout, int T)
{
    const int c    = (int)blockIdx.x;
    const int tid  = (int)threadIdx.x;
    const int lane = tid & 63;
    const int wid  = tid >> 6;              // 0..3
    __shared__ int offs[NE];
    __shared__ int wtot[SCHUNK / 64][NE];

    if (tid < NE) {
        int o = 0;
        for (int cc = 0; cc < c; ++cc) o += gcounts[cc * NE + tid];
        offs[tid] = o;
    }

    const int t = c * SCHUNK + tid;
    const unsigned p = packed[t];
    const int e1 = (int)(p & 15);
    const int e2 = (int)(p >> 4);

    unsigned long long bal[NE];
#pragma unroll
    for (int ee = 0; ee < NE; ++ee)
        bal[ee] = __ballot((e1 == ee) || (e2 == ee));

    if (lane < NE) wtot[wid][lane] = __popcll(bal[lane]);
    __syncthreads();

    const unsigned long long lt = (1ull << lane) - 1ull;
    int r1 = __popcll(bal[e1] & lt);
    int r2 = __popcll(bal[e2] & lt);
    for (int w = 0; w < wid; ++w) { r1 += wtot[w][e1]; r2 += wtot[w][e2]; }

    idxout[(size_t)e1 * T + offs[e1] + r1] = (float)t;
    idxout[(size_t)e2 * T + offs[e2] + r2] = (float)t;
}

extern "C" void kernel_launch(void* const* d_in, const int* in_sizes, int n_in,
                              void* d_out, int out_size, void* d_ws, size_t ws_size,
                              hipStream_t stream)
{
    const float* x = (const float*)d_in[0];
    const float* W = (const float*)d_in[1];
    const float* b = (const float*)d_in[2];
    float* out = (float*)d_out;

    const int T = in_sizes[0] / DDIM;       // 16384 tokens

    unsigned char* packed = (unsigned char*)d_ws;
    int* gcounts = (int*)((char*)d_ws + (((size_t)T + 255) & ~(size_t)255));

    float* idxout = out + (size_t)2 * T * NE;

    // 1) -1 fill + zero histograms (independent of pass_a)
    router_fill<<<(NE * T / 4) / 256, 256, 0, stream>>>(idxout, gcounts);

    // 2) logits/top2/dispatch + histogram: wave = 4 tokens, block = 16 tokens
    router_pass_a<<<T / 16, 256, 0, stream>>>(x, W, b, out, packed, gcounts, T);

    // 3) stable scatter of token ids
    router_scatter<<<T / SCHUNK, SCHUNK, 0, stream>>>(packed, gcounts, idxout, T);
}

// Round 6
// 373.330 us; speedup vs baseline: 1.9634x; 1.3103x over previous
//
#include <hip/hip_runtime.h>
#include <cstdint>
#include <cstddef>

#define DDIM 4096          // hidden dim
#define D4   1024          // float4 per token row
#define NE   16            // experts
#define KC4  128           // K-chunk in float4 (512 floats)
#define NCHUNK 8           // DDIM / 512
#define SCHUNK 256         // scatter chunk (tokens)

// async 16B global->LDS (lane's data lands at wave-uniform base + lane*16)
__device__ __forceinline__ void load_lds16(const void* g, void* l) {
    __builtin_amdgcn_global_load_lds(
        (const __attribute__((address_space(1))) unsigned int*)g,
        (__attribute__((address_space(3))) unsigned int*)l, 16, 0, 0);
}

__device__ __forceinline__ float dot4(float4 a, float4 w) {
    return a.x * w.x + a.y * w.y + a.z * w.z + a.w * w.w;
}

// ---------------------------------------------------------------------------
// Pass A: logits + top-2 softmax renorm + dispatch + packed pair byte +
// per-256-token-chunk expert histogram.
// Block = 4 waves = 32 tokens. W staged K-chunk-wise into DOUBLE-BUFFERED LDS
// via global_load_lds (zero VGPR round-trip); next chunk's stage issues right
// after the barrier so it overlaps this chunk's compute.
// Wave: tg = lane>>4 (4 groups x 2 tokens), kl = lane&15 (K-slice).
// acc = 2 x 16 = 32 VGPRs. NO unroll on the i-loop beyond 2 (R3/R4 spill
// post-mortem: unroll 4 x e-unroll 16 hoisted 64 ds_reads -> 256+ VGPR
// demand -> allocator collapse + scratch spill; WRITE_SIZE is the sentinel).
// ---------------------------------------------------------------------------
__global__ __launch_bounds__(256, 2) void router_pass_a(
    const float* __restrict__ x, const float* __restrict__ W,
    const float* __restrict__ b, float* __restrict__ out,
    unsigned char* __restrict__ packed, int* __restrict__ gcounts, int T)
{
    __shared__ float4 shW4[2 * NE * KC4];   // 2 x 32 KB double buffer

    const int tid  = (int)threadIdx.x;
    const int lane = tid & 63;
    const int wid  = tid >> 6;                    // wave in block
    const int tg   = lane >> 4;                   // token-pair group
    const int kl   = lane & 15;                   // K-lane
    const int tok0 = ((int)blockIdx.x * 4 + wid) * 8 + tg * 2;

    const float4* __restrict__ x4 = (const float4*)x;
    const float4* __restrict__ W4 = (const float4*)W;
    const float4* xr0 = x4 + (size_t)tok0 * D4;
    const float4* xr1 = xr0 + D4;

    float acc0[NE], acc1[NE];
#pragma unroll
    for (int e = 0; e < NE; ++e) { acc0[e] = 0.f; acc1[e] = 0.f; }

    // stage chunk 0 into buffer 0
#pragma unroll
    for (int j = 0; j < 8; ++j) {
        const int slot = wid * 8 + j;              // 0..31
        const int e = slot >> 1, half = slot & 1;
        load_lds16((const void*)(W4 + (size_t)e * D4 + half * 64 + lane),
                   (void*)(shW4 + slot * 64));
    }

    for (int kc = 0; kc < NCHUNK; ++kc) {
        __syncthreads();           // stage(kc) landed (barrier drains vmcnt)

        if (kc < NCHUNK - 1) {     // async stage of chunk kc+1 into other buf
            const int nb = ((kc + 1) & 1) * (NE * KC4);
#pragma unroll
            for (int j = 0; j < 8; ++j) {
                const int slot = wid * 8 + j;
                const int e = slot >> 1, half = slot & 1;
                load_lds16((const void*)(W4 + (size_t)e * D4 + (kc + 1) * KC4 +
                                         half * 64 + lane),
                           (void*)(shW4 + nb + slot * 64));
            }
        }

        const float4* bufp = shW4 + (kc & 1) * (NE * KC4);
        const int base = kc * KC4;
#pragma unroll 2
        for (int i = 0; i < 8; ++i) {
            const int f = base + kl + (i << 4);
            float4 a0 = xr0[f];
            float4 a1 = xr1[f];
            const float4* wrow = bufp + kl + (i << 4);
#pragma unroll
            for (int e = 0; e < NE; ++e) {
                float4 w = wrow[e * KC4];
                acc0[e] += dot4(a0, w);
                acc1[e] += dot4(a1, w);
            }
        }
    }

    // split-exchange within each 16-lane group: acc0[0]/acc1[0] end holding
    // the full sum for expert e == kl.
#pragma unroll
    for (int m = 8; m >= 1; m >>= 1) {
        const bool hi = (kl & m) != 0;
#pragma unroll
        for (int j = 0; j < m; ++j) {
            float s0 = hi ? acc0[j] : acc0[j + m];
            float k0 = hi ? acc0[j + m] : acc0[j];
            acc0[j] = k0 + __shfl_xor(s0, m, 64);
            float s1 = hi ? acc1[j] : acc1[j + m];
            float k1 = hi ? acc1[j + m] : acc1[j];
            acc1[j] = k1 + __shfl_xor(s1, m, 64);
        }
    }

    const float logit0 = acc0[0] + b[kl];
    const float logit1 = acc1[0] + b[kl];
    out[(size_t)tok0 * NE + kl]       = logit0;
    out[(size_t)(tok0 + 1) * NE + kl] = logit1;

    // top-2 merge over the 16-lane group (lower index wins ties), both tokens
    float m1a = logit0; int i1a = kl; float m2a = -__builtin_inff(); int i2a = NE;
    float m1b = logit1; int i1b = kl; float m2b = -__builtin_inff(); int i2b = NE;
#pragma unroll
    for (int m = 1; m <= 8; m <<= 1) {
        {
            float om1 = __shfl_xor(m1a, m, 64); int oi1 = __shfl_xor(i1a, m, 64);
            float om2 = __shfl_xor(m2a, m, 64); int oi2 = __shfl_xor(i2a, m, 64);
            bool aF = (m1a > om1) || (m1a == om1 && i1a < oi1);
            float n1v = aF ? m1a : om1; int n1i = aF ? i1a : oi1;
            float l1v = aF ? om1 : m1a; int l1i = aF ? oi1 : i1a;
            float c2v = aF ? m2a : om2; int c2i = aF ? i2a : oi2;
            bool s = (l1v > c2v) || (l1v == c2v && l1i < c2i);
            m1a = n1v; i1a = n1i; m2a = s ? l1v : c2v; i2a = s ? l1i : c2i;
        }
        {
            float om1 = __shfl_xor(m1b, m, 64); int oi1 = __shfl_xor(i1b, m, 64);
            float om2 = __shfl_xor(m2b, m, 64); int oi2 = __shfl_xor(i2b, m, 64);
            bool aF = (m1b > om1) || (m1b == om1 && i1b < oi1);
            float n1v = aF ? m1b : om1; int n1i = aF ? i1b : oi1;
            float l1v = aF ? om1 : m1b; int l1i = aF ? oi1 : i1b;
            float c2v = aF ? m2b : om2; int c2i = aF ? i2b : oi2;
            bool s = (l1v > c2v) || (l1v == c2v && l1i < c2i);
            m1b = n1v; i1b = n1i; m2b = s ? l1v : c2v; i2b = s ? l1i : c2i;
        }
    }

    float* __restrict__ disp = out + (size_t)T * NE;
    {
        const float q = expf(m2a - m1a);
        const float r1 = 1.f / (1.f + q), r2 = q / (1.f + q);
        disp[(size_t)tok0 * NE + kl] = (kl == i1a) ? r1 : ((kl == i2a) ? r2 : 0.f);
    }
    {
        const float q = expf(m2b - m1b);
        const float r1 = 1.f / (1.f + q), r2 = q / (1.f + q);
        disp[(size_t)(tok0 + 1) * NE + kl] = (kl == i1b) ? r1 : ((kl == i2b) ? r2 : 0.f);
    }

    if (kl == 0) {
        packed[tok0]     = (unsigned char)(i1a | (i2a << 4));
        packed[tok0 + 1] = (unsigned char)(i1b | (i2b << 4));
        int* gc = gcounts + (size_t)(tok0 >> 8) * NE;
        atomicAdd(&gc[i1a], 1);
        atomicAdd(&gc[i2a], 1);
        atomicAdd(&gc[i1b], 1);
        atomicAdd(&gc[i2b], 1);
    }
}

// ---------------------------------------------------------------------------
// Prologue: -1-fill expert_indices, zero the per-chunk histogram.
// Runs before pass_a (no dependency). 256 blocks x 256 threads.
// ---------------------------------------------------------------------------
__global__ __launch_bounds__(256) void router_fill(
    float* __restrict__ idxout, int* __restrict__ gcounts)
{
    const int t = (int)(blockIdx.x * 256 + threadIdx.x);   // 65536 threads
    float4* o4 = (float4*)idxout;                          // 1 MB of -1
    o4[t] = make_float4(-1.f, -1.f, -1.f, -1.f);
    if (t < (16384 / SCHUNK) * NE) gcounts[t] = 0;
}

// ---------------------------------------------------------------------------
// Scatter: stable compaction. 64 blocks x 256 tokens; 16-way-parallel
// exclusive prefix over gcounts, ballot/popcount intra-block ranking.
// ---------------------------------------------------------------------------
__global__ __launch_bounds__(SCHUNK) void router_scatter(
    const unsigned char* __restrict__ packed, const int* __restrict__ gcounts,
    float* __restrict__ idxout, int T)
{
    const int c    = (int)blockIdx.x;
    const int tid  = (int)threadIdx.x;
    const int lane = tid & 63;
    const int wid  = tid >> 6;              // 0..3
    __shared__ int offs[NE];
    __shared__ int wtot[SCHUNK / 64][NE];

    if (tid < NE) offs[tid] = 0;
    __syncthreads();
    {   // thread (e = tid&15, j = tid>>4) sums gcounts[cc][e], cc = j, j+16, ...
        const int e = tid & 15, j = tid >> 4;
        int s = 0;
        for (int cc = j; cc < c; cc += 16) s += gcounts[cc * NE + e];
        if (s) atomicAdd(&offs[e], s);
    }

    const int t = c * SCHUNK + tid;
    const unsigned p = packed[t];
    const int e1 = (int)(p & 15);
    const int e2 = (int)(p >> 4);

    unsigned long long bal[NE];
#pragma unroll
    for (int ee = 0; ee < NE; ++ee)
        bal[ee] = __ballot((e1 == ee) || (e2 == ee));

    if (lane < NE) wtot[wid][lane] = __popcll(bal[lane]);
    __syncthreads();   // covers offs accumulation + wtot

    const unsigned long long lt = (1ull << lane) - 1ull;
    int r1 = __popcll(bal[e1] & lt);
    int r2 = __popcll(bal[e2] & lt);
    for (int w = 0; w < wid; ++w) { r1 += wtot[w][e1]; r2 += wtot[w][e2]; }

    idxout[(size_t)e1 * T + offs[e1] + r1] = (float)t;
    idxout[(size_t)e2 * T + offs[e2] + r2] = (float)t;
}

extern "C" void kernel_launch(void* const* d_in, const int* in_sizes, int n_in,
                              void* d_out, int out_size, void* d_ws, size_t ws_size,
                              hipStream_t stream)
{
    const float* x = (const float*)d_in[0];
    const float* W = (const float*)d_in[1];
    const float* b = (const float*)d_in[2];
    float* out = (float*)d_out;

    const int T = in_sizes[0] / DDIM;       // 16384 tokens

    unsigned char* packed = (unsigned char*)d_ws;
    int* gcounts = (int*)((char*)d_ws + (((size_t)T + 255) & ~(size_t)255));

    float* idxout = out + (size_t)2 * T * NE;

    // 1) -1 fill + zero histograms (independent of pass_a)
    router_fill<<<(NE * T / 4) / 256, 256, 0, stream>>>(idxout, gcounts);

    // 2) logits/top2/dispatch + histogram: block = 4 waves = 32 tokens
    router_pass_a<<<T / 32, 256, 0, stream>>>(x, W, b, out, packed, gcounts, T);

    // 3) stable scatter of token ids
    router_scatter<<<T / SCHUNK, SCHUNK, 0, stream>>>(packed, gcounts, idxout, T);
}